// Round 10
// baseline (330.418 us; speedup 1.0000x reference)
//
#include <hip/hip_runtime.h>
#include <hip/hip_bf16.h>
#include <math.h>

#define Nn 20000
#define Ee 320000
#define INF_ 256
#define Hh 4
#define Cc 64
#define HC 256
#define NEG_SLOPE 0.2f
#define NB 79           // ceil(Nn/256)

using frag16 = __attribute__((ext_vector_type(8))) short;   // 8 bf16 (4 VGPRs)
using f32x4  = __attribute__((ext_vector_type(4))) float;

// async global->LDS 16B per lane; LDS dest = wave-uniform base + lane*16
__device__ __forceinline__ void async16(const void* g, void* l) {
    __builtin_amdgcn_global_load_lds(
        (const __attribute__((address_space(1))) unsigned int*)g,
        (__attribute__((address_space(3))) unsigned int*)l,
        16, 0, 0);
}

// ---------------- CSR build (6 small dispatches; grid.sync via kernel
// boundaries -- R8 showed coop grid.sync costs ~30us/barrier on 8 XCDs) ----

__global__ void init_deg(int* deg, int n) {
    int i = blockIdx.x * blockDim.x + threadIdx.x;
    if (i < n) deg[i] = 1;  // self-loop pre-counted
}

__global__ void hist_kernel(const int* __restrict__ dst, int ne, int* deg) {
    int e = blockIdx.x * blockDim.x + threadIdx.x;
    if (e < ne) atomicAdd(&deg[dst[e]], 1);
}

__global__ __launch_bounds__(256) void scan1(const int* __restrict__ deg,
                                             int* __restrict__ excl,
                                             int* __restrict__ bsum, int n) {
    int tid = threadIdx.x;
    int gid = blockIdx.x * 256 + tid;
    int lane = tid & 63;
    int v = (gid < n) ? deg[gid] : 0;
    int x = v;
    #pragma unroll
    for (int off = 1; off < 64; off <<= 1) {
        int y = __shfl_up(x, off, 64);
        if (lane >= off) x += y;
    }
    __shared__ int wsum[4];
    if (lane == 63) wsum[tid >> 6] = x;
    __syncthreads();
    int wadd = 0;
    for (int w = 0; w < (tid >> 6); ++w) wadd += wsum[w];
    int incl = x + wadd;
    if (gid < n) excl[gid] = incl - v;
    if (tid == 255) bsum[blockIdx.x] = incl;
}

__global__ void scan2(const int* __restrict__ bsum, int* __restrict__ boff, int nb) {
    int lane = threadIdx.x;
    int carry = 0;
    for (int base = 0; base < nb; base += 64) {
        int i = base + lane;
        int v = (i < nb) ? bsum[i] : 0;
        int x = v;
        #pragma unroll
        for (int off = 1; off < 64; off <<= 1) {
            int y = __shfl_up(x, off, 64);
            if (lane >= off) x += y;
        }
        if (i < nb) boff[i] = carry + x - v;
        carry += __shfl(x, 63, 64);
    }
    if (lane == 0) boff[nb] = carry;
}

__global__ void scan_add(int* __restrict__ row_start, int* __restrict__ cursor,
                         const int* __restrict__ boff, int n, int nb) {
    int gid = blockIdx.x * blockDim.x + threadIdx.x;
    if (gid < n) {
        int v = row_start[gid] + boff[gid >> 8];
        row_start[gid] = v;
        cursor[gid] = v;
    }
    if (gid == n) row_start[n] = boff[nb];
}

__global__ void scatter_kernel(const int* __restrict__ src, const int* __restrict__ dst,
                               int ne, int n, int* cursor, int* colx) {
    int e = blockIdx.x * blockDim.x + threadIdx.x;
    if (e < ne) {
        int d = dst[e];
        int pos = atomicAdd(&cursor[d], 1);
        colx[pos] = src[e];
    } else if (e < ne + n) {
        int node = e - ne;
        int pos = atomicAdd(&cursor[node], 1);
        colx[pos] = node;  // self-loop
    }
}

// ---------------- bf16 split-precision helpers ----------------

__device__ inline unsigned short bf16rn(float f) {
    unsigned u = __float_as_uint(f);
    unsigned r = (u + 0x7FFFu + ((u >> 16) & 1u)) >> 16;   // RTNE
    return (unsigned short)r;
}

__device__ inline void split1(float v, short& h, short& l) {
    unsigned short hh = bf16rn(v);
    float back = __uint_as_float(((unsigned)hh) << 16);
    unsigned short ll = bf16rn(v - back);
    h = (short)hh; l = (short)ll;
}

__device__ __forceinline__ float4 bf4_to_f4(ushort4 u) {
    return make_float4(__uint_as_float((unsigned)u.x << 16),
                       __uint_as_float((unsigned)u.y << 16),
                       __uint_as_float((unsigned)u.z << 16),
                       __uint_as_float((unsigned)u.w << 16));
}

// ---------------- fused prep: weight split (both layers) + x split ----------
// blocks 0..1023: weights (0-255 L1 Wl | 256-511 L1 Wr | 512-767 L2 Wl |
// 768-1023 L2 Wr). blocks 1024..: x -> Ah/Al (float4/thread).
// block 0 also zero-inits g (pool accum) + fcnt (last-block counter).

__global__ __launch_bounds__(256) void prep_kernel(const float* __restrict__ x,
                                                   const float* __restrict__ Wl1,
                                                   const float* __restrict__ Wr1,
                                                   const float* __restrict__ Wl2,
                                                   const float* __restrict__ Wr2,
                                                   short* __restrict__ WhT1,
                                                   short* __restrict__ WlT1,
                                                   short* __restrict__ WhT2,
                                                   short* __restrict__ WlT2,
                                                   short* __restrict__ Ah,
                                                   short* __restrict__ Al,
                                                   float* __restrict__ g,
                                                   int* __restrict__ fcnt, int n4) {
    int b = blockIdx.x;
    if (b < 1024) {
        int n = b & 255;
        int k = threadIdx.x;
        if (b == 0) {
            g[k] = 0.f;                  // HC == 256 == blockDim
            if (k == 0) *fcnt = 0;
        }
        const float* W = (b < 256) ? Wl1 : (b < 512) ? Wr1 : (b < 768) ? Wl2 : Wr2;
        short* Wh = (b < 512) ? WhT1 : WhT2;
        short* Wl = (b < 512) ? WlT1 : WlT2;
        int col = b & 511;
        float v = W[k * 256 + n];
        short h, l;
        split1(v, h, l);
        Wh[col * 256 + k] = h;
        Wl[col * 256 + k] = l;
    } else {
        int i = (b - 1024) * 256 + threadIdx.x;
        if (i >= n4) return;
        float4 v = ((const float4*)x)[i];
        short4 h, l;
        split1(v.x, h.x, l.x);
        split1(v.y, h.y, l.y);
        split1(v.z, h.z, l.z);
        split1(v.w, h.w, l.w);
        ((short4*)Ah)[i] = h;
        ((short4*)Al)[i] = l;
    }
}

// ---------------- bf16x3 MFMA fused GEMM, pipelined double-buffer ----------
// [XL | XR] = A @ [Wl | Wr],  C = Ah*Wh + Al*Wh + Ah*Wl (bf16x3 split).
// Single barrier per K-chunk: sync -> async-stage chunk c+1 (other buffer)
// -> compute chunk c. Staging latency overlaps compute; barrier count 16->8.
// XOR k-slot swizzle (slot = kb ^ ((row^(row>>2))&3)) applied on the GLOBAL
// fetch side (LDS write side is fixed to base+lane*16) so ds_read_b128 hits
// 8 distinct bank-groups (2-way aliasing = free; was 8-way = 2.94x).
// XL written bf16-hi only (halves gather traffic); XR fp32.

#define BK 32

__global__ __launch_bounds__(256) void mfma_gemm(const short* __restrict__ Ah,
                                                 const short* __restrict__ Al,
                                                 const short* __restrict__ WhT,
                                                 const short* __restrict__ WlT,
                                                 unsigned short* __restrict__ XLh,
                                                 float* __restrict__ XR) {
    __shared__ short As_h[2][128 * BK];
    __shared__ short As_l[2][128 * BK];
    __shared__ short Bs_h[2][128 * BK];
    __shared__ short Bs_l[2][128 * BK];
    int tid = threadIdx.x;
    int wave = tid >> 6, lane = tid & 63;
    int quad = lane >> 4, lc = lane & 15;
    int bx = blockIdx.x;                 // 0..3: concat col group (128 cols)
    int bm = blockIdx.y * 128;           // row group
    int cbase = (bx * 128) & 255;

    // staging coords: lane -> (local row = lane>>2, k-slot = lane&3);
    // global k-block = slot ^ swz(row) (bank-conflict swizzle)
    int sr0 = wave * 32 + (lane >> 2);
    int sr1 = sr0 + 16;
    int swz = ((lane >> 2) ^ (lane >> 4)) & 3;
    int koff = (((lane & 3) ^ swz)) * 8;
    int ga0 = bm + sr0; if (ga0 >= Nn) ga0 = Nn - 1;
    int ga1 = bm + sr1; if (ga1 >= Nn) ga1 = Nn - 1;
    int gb0 = bx * 128 + sr0;
    int gb1 = bx * 128 + sr1;
    int j0 = wave * 2, j1 = j0 + 1;

    const short* pA0h = Ah  + (size_t)ga0 * HC + koff;
    const short* pA1h = Ah  + (size_t)ga1 * HC + koff;
    const short* pA0l = Al  + (size_t)ga0 * HC + koff;
    const short* pA1l = Al  + (size_t)ga1 * HC + koff;
    const short* pB0h = WhT + (size_t)gb0 * HC + koff;
    const short* pB1h = WhT + (size_t)gb1 * HC + koff;
    const short* pB0l = WlT + (size_t)gb0 * HC + koff;
    const short* pB1l = WlT + (size_t)gb1 * HC + koff;

    auto stage = [&](int c, int d) {
        int k0 = c * BK;
        async16(pA0h + k0, &As_h[d][j0 * 512]);
        async16(pA1h + k0, &As_h[d][j1 * 512]);
        async16(pA0l + k0, &As_l[d][j0 * 512]);
        async16(pA1l + k0, &As_l[d][j1 * 512]);
        async16(pB0h + k0, &Bs_h[d][j0 * 512]);
        async16(pB1h + k0, &Bs_h[d][j1 * 512]);
        async16(pB0l + k0, &Bs_l[d][j0 * 512]);
        async16(pB1l + k0, &Bs_l[d][j1 * 512]);
    };

    // read-side swizzle: frag (row, kb=quad) lives at slot quad ^ rs(lc)
    int rs = (lc ^ (lc >> 2)) & 3;
    int akb = ((quad ^ rs)) * 8;
    int arow0 = (wave * 32 + lc) * BK + akb;
    int arow1 = (wave * 32 + 16 + lc) * BK + akb;

    f32x4 acc[2][8] = {};
    stage(0, 0);
    for (int c = 0; c < 8; ++c) {
        __syncthreads();                 // chunk c staged; prev compute done
        if (c < 7) stage(c + 1, (c + 1) & 1);
        int d = c & 1;
        frag16 a0h = *(const frag16*)&As_h[d][arow0];
        frag16 a1h = *(const frag16*)&As_h[d][arow1];
        frag16 a0l = *(const frag16*)&As_l[d][arow0];
        frag16 a1l = *(const frag16*)&As_l[d][arow1];
        #pragma unroll
        for (int t = 0; t < 8; ++t) {
            frag16 bh = *(const frag16*)&Bs_h[d][(t * 16 + lc) * BK + akb];
            frag16 bl = *(const frag16*)&Bs_l[d][(t * 16 + lc) * BK + akb];
            acc[0][t] = __builtin_amdgcn_mfma_f32_16x16x32_bf16(a0h, bh, acc[0][t], 0, 0, 0);
            acc[1][t] = __builtin_amdgcn_mfma_f32_16x16x32_bf16(a1h, bh, acc[1][t], 0, 0, 0);
            acc[0][t] = __builtin_amdgcn_mfma_f32_16x16x32_bf16(a0l, bh, acc[0][t], 0, 0, 0);
            acc[1][t] = __builtin_amdgcn_mfma_f32_16x16x32_bf16(a1l, bh, acc[1][t], 0, 0, 0);
            acc[0][t] = __builtin_amdgcn_mfma_f32_16x16x32_bf16(a0h, bl, acc[0][t], 0, 0, 0);
            acc[1][t] = __builtin_amdgcn_mfma_f32_16x16x32_bf16(a1h, bl, acc[1][t], 0, 0, 0);
        }
    }
    #pragma unroll
    for (int mt = 0; mt < 2; ++mt) {
        int rbase = bm + wave * 32 + mt * 16 + quad * 4;
        #pragma unroll
        for (int t = 0; t < 8; ++t) {
            int col = cbase + t * 16 + lc;
            #pragma unroll
            for (int r = 0; r < 4; ++r) {
                int rw = rbase + r;
                if (rw >= Nn) continue;
                if (bx < 2) XLh[(size_t)rw * HC + col] = bf16rn(acc[mt][t][r]);
                else        XR [(size_t)rw * HC + col] = acc[mt][t][r];
            }
        }
    }
}

// ---------------- GATv2 edge phase ----------------
// One wave per node (4 nodes/block). Lane holds 4 channels; head h = lanes
// 16h..16h+15. XL gathered bf16 (8 B/lane); XR/bias fp32.
// No-max softmax (scores bounded << 88); leaky(t)=0.6t+0.4|t|.
// 4-way edge unroll w/ independent partials for memory-level parallelism.

__device__ __forceinline__ float edge_score(const float4 v, const float4 xr,
                                            const float4 a06, const float4 a04) {
    float tx = v.x + xr.x, ty = v.y + xr.y, tz = v.z + xr.z, tw = v.w + xr.w;
    float p = a06.x * tx + a04.x * fabsf(tx);
    p += a06.y * ty + a04.y * fabsf(ty);
    p += a06.z * tz + a04.z * fabsf(tz);
    p += a06.w * tw + a04.w * fabsf(tw);
    p += __shfl_xor(p, 1, 64);
    p += __shfl_xor(p, 2, 64);
    p += __shfl_xor(p, 4, 64);
    p += __shfl_xor(p, 8, 64);             // per-head score in its 16 lanes
    return p;
}

__global__ __launch_bounds__(256) void gat_kernel(const ushort4* __restrict__ XL4,
                                                  const float4* __restrict__ XR4,
                                                  const int* __restrict__ row_start,
                                                  const int* __restrict__ colx,
                                                  const float4* __restrict__ att4,
                                                  const float4* __restrict__ bias4,
                                                  float4* __restrict__ Hout,
                                                  short4* __restrict__ Ahi,
                                                  short4* __restrict__ Alo,
                                                  int mode) {
    int wave = threadIdx.x >> 6, lane = threadIdx.x & 63;
    int node = blockIdx.x * 4 + wave;          // grid = Nn/4 exactly
    float4 xr = XR4[(size_t)node * 64 + lane];
    float4 a  = att4[lane];
    float4 a06 = make_float4(a.x * 0.6f, a.y * 0.6f, a.z * 0.6f, a.w * 0.6f);
    float4 a04 = make_float4(a.x * 0.4f, a.y * 0.4f, a.z * 0.4f, a.w * 0.4f);
    int e0 = row_start[node], e1 = row_start[node + 1];
    float l0 = 0.f, l1 = 0.f, l2 = 0.f, l3 = 0.f;
    float4 acc0 = make_float4(0.f, 0.f, 0.f, 0.f);
    float4 acc1 = make_float4(0.f, 0.f, 0.f, 0.f);
    float4 acc2 = make_float4(0.f, 0.f, 0.f, 0.f);
    float4 acc3 = make_float4(0.f, 0.f, 0.f, 0.f);
    int e = e0;
    for (; e + 3 < e1; e += 4) {
        int s0 = __builtin_amdgcn_readfirstlane(colx[e]);
        int s1 = __builtin_amdgcn_readfirstlane(colx[e + 1]);
        int s2 = __builtin_amdgcn_readfirstlane(colx[e + 2]);
        int s3 = __builtin_amdgcn_readfirstlane(colx[e + 3]);
        float4 v0 = bf4_to_f4(XL4[(size_t)s0 * 64 + lane]);
        float4 v1 = bf4_to_f4(XL4[(size_t)s1 * 64 + lane]);
        float4 v2 = bf4_to_f4(XL4[(size_t)s2 * 64 + lane]);
        float4 v3 = bf4_to_f4(XL4[(size_t)s3 * 64 + lane]);
        float pe0 = __expf(edge_score(v0, xr, a06, a04));
        float pe1 = __expf(edge_score(v1, xr, a06, a04));
        float pe2 = __expf(edge_score(v2, xr, a06, a04));
        float pe3 = __expf(edge_score(v3, xr, a06, a04));
        l0 += pe0; l1 += pe1; l2 += pe2; l3 += pe3;
        acc0.x += pe0 * v0.x; acc0.y += pe0 * v0.y; acc0.z += pe0 * v0.z; acc0.w += pe0 * v0.w;
        acc1.x += pe1 * v1.x; acc1.y += pe1 * v1.y; acc1.z += pe1 * v1.z; acc1.w += pe1 * v1.w;
        acc2.x += pe2 * v2.x; acc2.y += pe2 * v2.y; acc2.z += pe2 * v2.z; acc2.w += pe2 * v2.w;
        acc3.x += pe3 * v3.x; acc3.y += pe3 * v3.y; acc3.z += pe3 * v3.z; acc3.w += pe3 * v3.w;
    }
    for (; e < e1; ++e) {
        int s0 = __builtin_amdgcn_readfirstlane(colx[e]);
        float4 v0 = bf4_to_f4(XL4[(size_t)s0 * 64 + lane]);
        float pe0 = __expf(edge_score(v0, xr, a06, a04));
        l0 += pe0;
        acc0.x += pe0 * v0.x; acc0.y += pe0 * v0.y;
        acc0.z += pe0 * v0.z; acc0.w += pe0 * v0.w;
    }
    float rl = 1.f / (l0 + l1 + l2 + l3);
    float4 b = bias4[lane];
    float4 o = make_float4(fmaxf((acc0.x + acc1.x + acc2.x + acc3.x) * rl + b.x, 0.f),
                           fmaxf((acc0.y + acc1.y + acc2.y + acc3.y) * rl + b.y, 0.f),
                           fmaxf((acc0.z + acc1.z + acc2.z + acc3.z) * rl + b.z, 0.f),
                           fmaxf((acc0.w + acc1.w + acc2.w + acc3.w) * rl + b.w, 0.f));
    size_t oidx = (size_t)node * 64 + lane;
    if (mode) {
        short4 h4, l4;
        split1(o.x, h4.x, l4.x);
        split1(o.y, h4.y, l4.y);
        split1(o.z, h4.z, l4.z);
        split1(o.w, h4.w, l4.w);
        Ahi[oidx] = h4;
        Alo[oidx] = l4;
    } else {
        Hout[oidx] = o;
    }
}

// ---------------- fused pooling + FC (last-block pattern) ----------------
// g and fcnt are zero-inited by prep_kernel at the start of the launch.

__global__ __launch_bounds__(256) void colsum_fc(const float* __restrict__ Hmat,
                                                 float* __restrict__ g,
                                                 int* __restrict__ fcnt,
                                                 const float* __restrict__ Wfc,
                                                 const float* __restrict__ bfc,
                                                 float* __restrict__ out, float invN) {
    int ch = threadIdx.x;
    float s = 0.f;
    for (int r = blockIdx.x; r < Nn; r += gridDim.x)
        s += Hmat[(size_t)r * HC + ch];
    atomicAdd(&g[ch], s);
    __threadfence();
    __shared__ int last;
    if (ch == 0) last = (atomicAdd(fcnt, 1) == (int)gridDim.x - 1);
    __syncthreads();
    if (!last) return;
    // last block: all partial sums visible; read via atomic (L1-bypass)
    float gv = atomicAdd(&g[ch], 0.f) * invN;
    float p0 = gv * Wfc[2 * ch];
    float p1 = gv * Wfc[2 * ch + 1];
    #pragma unroll
    for (int off = 32; off > 0; off >>= 1) {
        p0 += __shfl_xor(p0, off, 64);
        p1 += __shfl_xor(p1, off, 64);
    }
    __shared__ float s0[4], s1[4];
    if ((ch & 63) == 0) { s0[ch >> 6] = p0; s1[ch >> 6] = p1; }
    __syncthreads();
    if (ch == 0) {
        out[0] = s0[0] + s0[1] + s0[2] + s0[3] + bfc[0];
        out[1] = s1[0] + s1[1] + s1[2] + s1[3] + bfc[1];
    }
}

// ---------------- launch ----------------

extern "C" void kernel_launch(void* const* d_in, const int* in_sizes, int n_in,
                              void* d_out, int out_size, void* d_ws, size_t ws_size,
                              hipStream_t stream) {
    const float* x    = (const float*)d_in[0];
    const int*   eidx = (const int*)d_in[1];   // (2,E) row-major: [src | dst]
    const float* Wl1  = (const float*)d_in[2];
    const float* Wr1  = (const float*)d_in[3];
    const float* att1 = (const float*)d_in[4];
    const float* b1   = (const float*)d_in[5];
    const float* Wl2  = (const float*)d_in[6];
    const float* Wr2  = (const float*)d_in[7];
    const float* att2 = (const float*)d_in[8];
    const float* b2   = (const float*)d_in[9];
    const float* Wfc  = (const float*)d_in[10];
    const float* bfc  = (const float*)d_in[11];
    float* out = (float*)d_out;

    const int* srcv = eidx;
    const int* dstv = eidx + Ee;

    // workspace layout (~75 MB)
    size_t NHC = (size_t)Nn * HC;
    float* XR = (float*)d_ws;
    float* Hb = XR + NHC;
    float* g  = Hb + NHC;
    unsigned short* XLh = (unsigned short*)(g + HC);
    short* Ah   = (short*)(XLh + NHC);
    short* Al   = Ah + NHC;
    short* WhT1 = Al + NHC;                    // 512*256 concat [Wl|Wr]^T per layer
    short* WlT1 = WhT1 + 512 * 256;
    short* WhT2 = WlT1 + 512 * 256;
    short* WlT2 = WhT2 + 512 * 256;
    int* deg       = (int*)(WlT2 + 512 * 256);
    int* row_start = deg + Nn;
    int* cursor    = row_start + (Nn + 1);
    int* colx      = cursor + Nn;              // Ee + Nn entries
    int* bsum      = colx + (Ee + Nn);
    int* boff      = bsum + 128;               // NB+1 entries
    int* fcnt      = boff + 128;

    const int N4 = (int)(NHC / 4);             // 1,280,000 (5000 x-split blocks)

    // CSR build (6 small dispatches)
    init_deg<<<(Nn + 255) / 256, 256, 0, stream>>>(deg, Nn);
    hist_kernel<<<(Ee + 255) / 256, 256, 0, stream>>>(dstv, Ee, deg);
    scan1<<<NB, 256, 0, stream>>>(deg, row_start, bsum, Nn);
    scan2<<<1, 64, 0, stream>>>(bsum, boff, NB);
    scan_add<<<(Nn + 256) / 256, 256, 0, stream>>>(row_start, cursor, boff, Nn, NB);
    scatter_kernel<<<(Ee + Nn + 255) / 256, 256, 0, stream>>>(srcv, dstv, Ee, Nn, cursor, colx);

    // weight split (both layers) + layer-1 input split + g/fcnt zero: 1 dispatch
    prep_kernel<<<1024 + N4 / 256, 256, 0, stream>>>(x, Wl1, Wr1, Wl2, Wr2,
                                                     WhT1, WlT1, WhT2, WlT2,
                                                     Ah, Al, g, fcnt, N4);

    dim3 ggrid(4, (Nn + 127) / 128);           // 4 x 157

    // layer 1 (gat writes bf16 split directly -> layer-2 GEMM input)
    mfma_gemm<<<ggrid, 256, 0, stream>>>(Ah, Al, WhT1, WlT1, XLh, XR);
    gat_kernel<<<Nn / 4, 256, 0, stream>>>((const ushort4*)XLh, (const float4*)XR,
                                           row_start, colx, (const float4*)att1,
                                           (const float4*)b1, (float4*)Hb,
                                           (short4*)Ah, (short4*)Al, 1);

    // layer 2
    mfma_gemm<<<ggrid, 256, 0, stream>>>(Ah, Al, WhT2, WlT2, XLh, XR);
    gat_kernel<<<Nn / 4, 256, 0, stream>>>((const ushort4*)XLh, (const float4*)XR,
                                           row_start, colx, (const float4*)att2,
                                           (const float4*)b2, (float4*)Hb,
                                           (short4*)Ah, (short4*)Al, 0);

    // pool + fc (fused, last-block pattern)
    colsum_fc<<<256, 256, 0, stream>>>(Hb, g, fcnt, Wfc, bfc, out, 1.0f / Nn);
}

// Round 11
// 322.177 us; speedup vs baseline: 1.0256x; 1.0256x over previous
//
#include <hip/hip_runtime.h>
#include <hip/hip_bf16.h>
#include <math.h>

#define Nn 20000
#define Ee 320000
#define INF_ 256
#define Hh 4
#define Cc 64
#define HC 256
#define NEG_SLOPE 0.2f
#define NB 79           // ceil(Nn/256)

using frag16 = __attribute__((ext_vector_type(8))) short;   // 8 bf16 (4 VGPRs)
using f32x4  = __attribute__((ext_vector_type(4))) float;

// async global->LDS 16B per lane; LDS dest = wave-uniform base + lane*16
__device__ __forceinline__ void async16(const void* g, void* l) {
    __builtin_amdgcn_global_load_lds(
        (const __attribute__((address_space(1))) unsigned int*)g,
        (__attribute__((address_space(3))) unsigned int*)l,
        16, 0, 0);
}

// ---------------- CSR build (6 small dispatches; R8: coop grid.sync costs
// ~30us/barrier on 8 XCDs -- kernel boundaries are the cheap grid barrier) --

__global__ void init_deg(int* deg, int n) {
    int i = blockIdx.x * blockDim.x + threadIdx.x;
    if (i < n) deg[i] = 1;  // self-loop pre-counted
}

__global__ void hist_kernel(const int* __restrict__ dst, int ne, int* deg) {
    int e = blockIdx.x * blockDim.x + threadIdx.x;
    if (e < ne) atomicAdd(&deg[dst[e]], 1);
}

__global__ __launch_bounds__(256) void scan1(const int* __restrict__ deg,
                                             int* __restrict__ excl,
                                             int* __restrict__ bsum, int n) {
    int tid = threadIdx.x;
    int gid = blockIdx.x * 256 + tid;
    int lane = tid & 63;
    int v = (gid < n) ? deg[gid] : 0;
    int x = v;
    #pragma unroll
    for (int off = 1; off < 64; off <<= 1) {
        int y = __shfl_up(x, off, 64);
        if (lane >= off) x += y;
    }
    __shared__ int wsum[4];
    if (lane == 63) wsum[tid >> 6] = x;
    __syncthreads();
    int wadd = 0;
    for (int w = 0; w < (tid >> 6); ++w) wadd += wsum[w];
    int incl = x + wadd;
    if (gid < n) excl[gid] = incl - v;
    if (tid == 255) bsum[blockIdx.x] = incl;
}

__global__ void scan2(const int* __restrict__ bsum, int* __restrict__ boff, int nb) {
    int lane = threadIdx.x;
    int carry = 0;
    for (int base = 0; base < nb; base += 64) {
        int i = base + lane;
        int v = (i < nb) ? bsum[i] : 0;
        int x = v;
        #pragma unroll
        for (int off = 1; off < 64; off <<= 1) {
            int y = __shfl_up(x, off, 64);
            if (lane >= off) x += y;
        }
        if (i < nb) boff[i] = carry + x - v;
        carry += __shfl(x, 63, 64);
    }
    if (lane == 0) boff[nb] = carry;
}

__global__ void scan_add(int* __restrict__ row_start, int* __restrict__ cursor,
                         const int* __restrict__ boff, int n, int nb) {
    int gid = blockIdx.x * blockDim.x + threadIdx.x;
    if (gid < n) {
        int v = row_start[gid] + boff[gid >> 8];
        row_start[gid] = v;
        cursor[gid] = v;
    }
    if (gid == n) row_start[n] = boff[nb];
}

__global__ void scatter_kernel(const int* __restrict__ src, const int* __restrict__ dst,
                               int ne, int n, int* cursor, int* colx) {
    int e = blockIdx.x * blockDim.x + threadIdx.x;
    if (e < ne) {
        int d = dst[e];
        int pos = atomicAdd(&cursor[d], 1);
        colx[pos] = src[e];
    } else if (e < ne + n) {
        int node = e - ne;
        int pos = atomicAdd(&cursor[node], 1);
        colx[pos] = node;  // self-loop
    }
}

// ---------------- bf16 split-precision helpers ----------------

__device__ inline unsigned short bf16rn(float f) {
    unsigned u = __float_as_uint(f);
    unsigned r = (u + 0x7FFFu + ((u >> 16) & 1u)) >> 16;   // RTNE
    return (unsigned short)r;
}

__device__ inline void split1(float v, short& h, short& l) {
    unsigned short hh = bf16rn(v);
    float back = __uint_as_float(((unsigned)hh) << 16);
    unsigned short ll = bf16rn(v - back);
    h = (short)hh; l = (short)ll;
}

__device__ __forceinline__ float4 bf4_to_f4(ushort4 u) {
    return make_float4(__uint_as_float((unsigned)u.x << 16),
                       __uint_as_float((unsigned)u.y << 16),
                       __uint_as_float((unsigned)u.z << 16),
                       __uint_as_float((unsigned)u.w << 16));
}

// ---------------- fused prep: weight split (both layers) + x split ----------

__global__ __launch_bounds__(256) void prep_kernel(const float* __restrict__ x,
                                                   const float* __restrict__ Wl1,
                                                   const float* __restrict__ Wr1,
                                                   const float* __restrict__ Wl2,
                                                   const float* __restrict__ Wr2,
                                                   short* __restrict__ WhT1,
                                                   short* __restrict__ WlT1,
                                                   short* __restrict__ WhT2,
                                                   short* __restrict__ WlT2,
                                                   short* __restrict__ Ah,
                                                   short* __restrict__ Al,
                                                   float* __restrict__ g,
                                                   int* __restrict__ fcnt, int n4) {
    int b = blockIdx.x;
    if (b < 1024) {
        int n = b & 255;
        int k = threadIdx.x;
        if (b == 0) {
            g[k] = 0.f;                  // HC == 256 == blockDim
            if (k == 0) *fcnt = 0;
        }
        const float* W = (b < 256) ? Wl1 : (b < 512) ? Wr1 : (b < 768) ? Wl2 : Wr2;
        short* Wh = (b < 512) ? WhT1 : WhT2;
        short* Wl = (b < 512) ? WlT1 : WlT2;
        int col = b & 511;
        float v = W[k * 256 + n];
        short h, l;
        split1(v, h, l);
        Wh[col * 256 + k] = h;
        Wl[col * 256 + k] = l;
    } else {
        int i = (b - 1024) * 256 + threadIdx.x;
        if (i >= n4) return;
        float4 v = ((const float4*)x)[i];
        short4 h, l;
        split1(v.x, h.x, l.x);
        split1(v.y, h.y, l.y);
        split1(v.z, h.z, l.z);
        split1(v.w, h.w, l.w);
        ((short4*)Ah)[i] = h;
        ((short4*)Al)[i] = l;
    }
}

// ---------------- bf16x3 MFMA fused GEMM, 64x64 tiles, pipelined dbuf -------
// [XL | XR] = A @ [Wl | Wr],  C = Ah*Wh + Al*Wh + Ah*Wl (bf16x3 split).
// 64x64 tile -> 2504 blocks, 32 KB LDS dbuf -> 5 blocks/CU (vs 2.4 at 128).
// XCD-aware flat-grid swizzle: row-blocks == XCD (id%8), col fastest -> each
// XCD streams its 2.5 MB A-slice + 1 MB B once through its own L2.
// Single barrier/chunk: sync -> stage c+1 (other buf) -> compute c.
// XOR k-slot swizzle on fetch & read sides -> ds_read_b128 2-way only.
// Wave w stages tile w (A_h/A_l/B_h/B_l) and computes n-strip w.

#define BK 32

__global__ __launch_bounds__(256) void mfma_gemm(const short* __restrict__ Ah,
                                                 const short* __restrict__ Al,
                                                 const short* __restrict__ WhT,
                                                 const short* __restrict__ WlT,
                                                 unsigned short* __restrict__ XLh,
                                                 float* __restrict__ XR) {
    __shared__ short S[2][4][64 * BK];        // [buf][tile: Ah,Al,Bh,Bl]
    int tid = threadIdx.x;
    int wave = tid >> 6, lane = tid & 63;
    int quad = lane >> 4, lc = lane & 15;

    int flat = blockIdx.x;                    // 0..2559 (320 row-blocks x 8)
    int xcd = flat & 7;
    int slot = flat >> 3;                     // 0..319
    int rb = xcd + 8 * (slot >> 3);           // row-block; ==xcd (mod 8)
    int bxc = slot & 7;                       // col-group (64 concat cols)
    int bm = rb * 64;
    if (bm >= Nn) return;                     // padding blocks (rb >= 313)
    int cbase = (bxc * 64) & 255;

    // staging: wave stages its tile with 4 async16 calls; call i covers rows
    // i*16 + (lane>>2), 16B k-slot (lane&3) XOR-swizzled.
    int srow = lane >> 2;
    int swz = ((lane >> 2) ^ (lane >> 4)) & 3;
    int koff = ((lane & 3) ^ swz) * 8;
    const short* mat = (wave == 0) ? Ah : (wave == 1) ? Al
                     : (wave == 2) ? WhT : WlT;
    int grow_base = (wave < 2) ? bm : bxc * 64;
    const short* gp[4];
    #pragma unroll
    for (int i = 0; i < 4; ++i) {
        int grow = grow_base + i * 16 + srow;
        if (wave < 2 && grow >= Nn) grow = Nn - 1;   // clamp (rows independent)
        gp[i] = mat + (size_t)grow * HC + koff;
    }

    auto stage = [&](int c, int d) {
        int k0 = c * BK;
        #pragma unroll
        for (int i = 0; i < 4; ++i)
            async16(gp[i] + k0, &S[d][wave][i * 512]);
    };

    // read-side swizzle: frag (row, kb=quad) lives at slot quad ^ rs(lc)
    int rs = (lc ^ (lc >> 2)) & 3;
    int akb = (quad ^ rs) * 8;

    f32x4 acc[4] = {};
    stage(0, 0);
    for (int c = 0; c < 8; ++c) {
        __syncthreads();                 // chunk c staged; prev compute done
        if (c < 7) stage(c + 1, (c + 1) & 1);
        int d = c & 1;
        frag16 bh = *(const frag16*)&S[d][2][(wave * 16 + lc) * BK + akb];
        frag16 bl = *(const frag16*)&S[d][3][(wave * 16 + lc) * BK + akb];
        #pragma unroll
        for (int mt = 0; mt < 4; ++mt) {
            frag16 amh = *(const frag16*)&S[d][0][(mt * 16 + lc) * BK + akb];
            frag16 aml = *(const frag16*)&S[d][1][(mt * 16 + lc) * BK + akb];
            acc[mt] = __builtin_amdgcn_mfma_f32_16x16x32_bf16(amh, bh, acc[mt], 0, 0, 0);
            acc[mt] = __builtin_amdgcn_mfma_f32_16x16x32_bf16(aml, bh, acc[mt], 0, 0, 0);
            acc[mt] = __builtin_amdgcn_mfma_f32_16x16x32_bf16(amh, bl, acc[mt], 0, 0, 0);
        }
    }
    // epilogue: wave's cols = cbase + wave*16 + lc; rows = bm + mt*16 + quad*4 + r
    int col = cbase + wave * 16 + lc;
    #pragma unroll
    for (int mt = 0; mt < 4; ++mt) {
        int rbase = bm + mt * 16 + quad * 4;
        #pragma unroll
        for (int r = 0; r < 4; ++r) {
            int rw = rbase + r;
            if (rw >= Nn) continue;
            if (bxc < 4) XLh[(size_t)rw * HC + col] = bf16rn(acc[mt][r]);
            else         XR [(size_t)rw * HC + col] = acc[mt][r];
        }
    }
}

// ---------------- GATv2 edge phase ----------------
// One wave per node (4 nodes/block). Lane holds 4 channels; head h = lanes
// 16h..16h+15. XL gathered bf16 (8 B/lane); XR/bias fp32.
// No-max softmax (scores bounded << 88); leaky(t)=0.6t+0.4|t|.
// 8-way edge unroll (8 gathers in flight/wave; 4 accumulator partials).

__device__ __forceinline__ float edge_score(const float4 v, const float4 xr,
                                            const float4 a06, const float4 a04) {
    float tx = v.x + xr.x, ty = v.y + xr.y, tz = v.z + xr.z, tw = v.w + xr.w;
    float p = a06.x * tx + a04.x * fabsf(tx);
    p += a06.y * ty + a04.y * fabsf(ty);
    p += a06.z * tz + a04.z * fabsf(tz);
    p += a06.w * tw + a04.w * fabsf(tw);
    p += __shfl_xor(p, 1, 64);
    p += __shfl_xor(p, 2, 64);
    p += __shfl_xor(p, 4, 64);
    p += __shfl_xor(p, 8, 64);             // per-head score in its 16 lanes
    return p;
}

__global__ __launch_bounds__(256) void gat_kernel(const ushort4* __restrict__ XL4,
                                                  const float4* __restrict__ XR4,
                                                  const int* __restrict__ row_start,
                                                  const int* __restrict__ colx,
                                                  const float4* __restrict__ att4,
                                                  const float4* __restrict__ bias4,
                                                  float4* __restrict__ Hout,
                                                  short4* __restrict__ Ahi,
                                                  short4* __restrict__ Alo,
                                                  int mode) {
    int wave = threadIdx.x >> 6, lane = threadIdx.x & 63;
    int node = blockIdx.x * 4 + wave;          // grid = Nn/4 exactly
    float4 xr = XR4[(size_t)node * 64 + lane];
    float4 a  = att4[lane];
    float4 a06 = make_float4(a.x * 0.6f, a.y * 0.6f, a.z * 0.6f, a.w * 0.6f);
    float4 a04 = make_float4(a.x * 0.4f, a.y * 0.4f, a.z * 0.4f, a.w * 0.4f);
    int e0 = row_start[node], e1 = row_start[node + 1];
    float lw[4] = {0.f, 0.f, 0.f, 0.f};
    float4 acc[4];
    #pragma unroll
    for (int j = 0; j < 4; ++j) acc[j] = make_float4(0.f, 0.f, 0.f, 0.f);

    int e = e0;
    for (; e + 7 < e1; e += 8) {
        int s[8];
        #pragma unroll
        for (int j = 0; j < 8; ++j) s[j] = __builtin_amdgcn_readfirstlane(colx[e + j]);
        float4 v[8];
        #pragma unroll
        for (int j = 0; j < 8; ++j) v[j] = bf4_to_f4(XL4[(size_t)s[j] * 64 + lane]);
        #pragma unroll
        for (int j = 0; j < 8; ++j) {
            float pe = __expf(edge_score(v[j], xr, a06, a04));
            lw[j & 3] += pe;
            acc[j & 3].x += pe * v[j].x;
            acc[j & 3].y += pe * v[j].y;
            acc[j & 3].z += pe * v[j].z;
            acc[j & 3].w += pe * v[j].w;
        }
    }
    for (; e + 3 < e1; e += 4) {
        int s[4];
        #pragma unroll
        for (int j = 0; j < 4; ++j) s[j] = __builtin_amdgcn_readfirstlane(colx[e + j]);
        float4 v[4];
        #pragma unroll
        for (int j = 0; j < 4; ++j) v[j] = bf4_to_f4(XL4[(size_t)s[j] * 64 + lane]);
        #pragma unroll
        for (int j = 0; j < 4; ++j) {
            float pe = __expf(edge_score(v[j], xr, a06, a04));
            lw[j] += pe;
            acc[j].x += pe * v[j].x;
            acc[j].y += pe * v[j].y;
            acc[j].z += pe * v[j].z;
            acc[j].w += pe * v[j].w;
        }
    }
    for (; e < e1; ++e) {
        int s0 = __builtin_amdgcn_readfirstlane(colx[e]);
        float4 v0 = bf4_to_f4(XL4[(size_t)s0 * 64 + lane]);
        float pe = __expf(edge_score(v0, xr, a06, a04));
        lw[0] += pe;
        acc[0].x += pe * v0.x; acc[0].y += pe * v0.y;
        acc[0].z += pe * v0.z; acc[0].w += pe * v0.w;
    }
    float rl = 1.f / (lw[0] + lw[1] + lw[2] + lw[3]);
    float4 b = bias4[lane];
    float4 o = make_float4(
        fmaxf((acc[0].x + acc[1].x + acc[2].x + acc[3].x) * rl + b.x, 0.f),
        fmaxf((acc[0].y + acc[1].y + acc[2].y + acc[3].y) * rl + b.y, 0.f),
        fmaxf((acc[0].z + acc[1].z + acc[2].z + acc[3].z) * rl + b.z, 0.f),
        fmaxf((acc[0].w + acc[1].w + acc[2].w + acc[3].w) * rl + b.w, 0.f));
    size_t oidx = (size_t)node * 64 + lane;
    if (mode) {
        short4 h4, l4;
        split1(o.x, h4.x, l4.x);
        split1(o.y, h4.y, l4.y);
        split1(o.z, h4.z, l4.z);
        split1(o.w, h4.w, l4.w);
        Ahi[oidx] = h4;
        Alo[oidx] = l4;
    } else {
        Hout[oidx] = o;
    }
}

// ---------------- fused pooling + FC (last-block pattern) ----------------
// g and fcnt are zero-inited by prep_kernel at the start of the launch.

__global__ __launch_bounds__(256) void colsum_fc(const float* __restrict__ Hmat,
                                                 float* __restrict__ g,
                                                 int* __restrict__ fcnt,
                                                 const float* __restrict__ Wfc,
                                                 const float* __restrict__ bfc,
                                                 float* __restrict__ out, float invN) {
    int ch = threadIdx.x;
    float s = 0.f;
    for (int r = blockIdx.x; r < Nn; r += gridDim.x)
        s += Hmat[(size_t)r * HC + ch];
    atomicAdd(&g[ch], s);
    __threadfence();
    __shared__ int last;
    if (ch == 0) last = (atomicAdd(fcnt, 1) == (int)gridDim.x - 1);
    __syncthreads();
    if (!last) return;
    // last block: all partial sums visible; read via atomic (L1-bypass)
    float gv = atomicAdd(&g[ch], 0.f) * invN;
    float p0 = gv * Wfc[2 * ch];
    float p1 = gv * Wfc[2 * ch + 1];
    #pragma unroll
    for (int off = 32; off > 0; off >>= 1) {
        p0 += __shfl_xor(p0, off, 64);
        p1 += __shfl_xor(p1, off, 64);
    }
    __shared__ float s0[4], s1[4];
    if ((ch & 63) == 0) { s0[ch >> 6] = p0; s1[ch >> 6] = p1; }
    __syncthreads();
    if (ch == 0) {
        out[0] = s0[0] + s0[1] + s0[2] + s0[3] + bfc[0];
        out[1] = s1[0] + s1[1] + s1[2] + s1[3] + bfc[1];
    }
}

// ---------------- launch ----------------

extern "C" void kernel_launch(void* const* d_in, const int* in_sizes, int n_in,
                              void* d_out, int out_size, void* d_ws, size_t ws_size,
                              hipStream_t stream) {
    const float* x    = (const float*)d_in[0];
    const int*   eidx = (const int*)d_in[1];   // (2,E) row-major: [src | dst]
    const float* Wl1  = (const float*)d_in[2];
    const float* Wr1  = (const float*)d_in[3];
    const float* att1 = (const float*)d_in[4];
    const float* b1   = (const float*)d_in[5];
    const float* Wl2  = (const float*)d_in[6];
    const float* Wr2  = (const float*)d_in[7];
    const float* att2 = (const float*)d_in[8];
    const float* b2   = (const float*)d_in[9];
    const float* Wfc  = (const float*)d_in[10];
    const float* bfc  = (const float*)d_in[11];
    float* out = (float*)d_out;

    const int* srcv = eidx;
    const int* dstv = eidx + Ee;

    // workspace layout (~75 MB)
    size_t NHC = (size_t)Nn * HC;
    float* XR = (float*)d_ws;
    float* Hb = XR + NHC;
    float* g  = Hb + NHC;
    unsigned short* XLh = (unsigned short*)(g + HC);
    short* Ah   = (short*)(XLh + NHC);
    short* Al   = Ah + NHC;
    short* WhT1 = Al + NHC;                    // 512*256 concat [Wl|Wr]^T per layer
    short* WlT1 = WhT1 + 512 * 256;
    short* WhT2 = WlT1 + 512 * 256;
    short* WlT2 = WhT2 + 512 * 256;
    int* deg       = (int*)(WlT2 + 512 * 256);
    int* row_start = deg + Nn;
    int* cursor    = row_start + (Nn + 1);
    int* colx      = cursor + Nn;              // Ee + Nn entries
    int* bsum      = colx + (Ee + Nn);
    int* boff      = bsum + 128;               // NB+1 entries
    int* fcnt      = boff + 128;

    const int N4 = (int)(NHC / 4);             // 1,280,000 (5000 x-split blocks)

    // CSR build (6 small dispatches)
    init_deg<<<(Nn + 255) / 256, 256, 0, stream>>>(deg, Nn);
    hist_kernel<<<(Ee + 255) / 256, 256, 0, stream>>>(dstv, Ee, deg);
    scan1<<<NB, 256, 0, stream>>>(deg, row_start, bsum, Nn);
    scan2<<<1, 64, 0, stream>>>(bsum, boff, NB);
    scan_add<<<(Nn + 256) / 256, 256, 0, stream>>>(row_start, cursor, boff, Nn, NB);
    scatter_kernel<<<(Ee + Nn + 255) / 256, 256, 0, stream>>>(srcv, dstv, Ee, Nn, cursor, colx);

    // weight split (both layers) + layer-1 input split + g/fcnt zero: 1 dispatch
    prep_kernel<<<1024 + N4 / 256, 256, 0, stream>>>(x, Wl1, Wr1, Wl2, Wr2,
                                                     WhT1, WlT1, WhT2, WlT2,
                                                     Ah, Al, g, fcnt, N4);

    // 64x64 tiles, XCD-swizzled flat grid: 320 row-blocks x 8 col-groups
    const int GEMM_BLOCKS = 320 * 8;

    // layer 1 (gat writes bf16 split directly -> layer-2 GEMM input)
    mfma_gemm<<<GEMM_BLOCKS, 256, 0, stream>>>(Ah, Al, WhT1, WlT1, XLh, XR);
    gat_kernel<<<Nn / 4, 256, 0, stream>>>((const ushort4*)XLh, (const float4*)XR,
                                           row_start, colx, (const float4*)att1,
                                           (const float4*)b1, (float4*)Hb,
                                           (short4*)Ah, (short4*)Al, 1);

    // layer 2
    mfma_gemm<<<GEMM_BLOCKS, 256, 0, stream>>>(Ah, Al, WhT2, WlT2, XLh, XR);
    gat_kernel<<<Nn / 4, 256, 0, stream>>>((const ushort4*)XLh, (const float4*)XR,
                                           row_start, colx, (const float4*)att2,
                                           (const float4*)b2, (float4*)Hb,
                                           (short4*)Ah, (short4*)Al, 0);

    // pool + fc (fused, last-block pattern)
    colsum_fc<<<256, 256, 0, stream>>>(Hb, g, fcnt, Wfc, bfc, out, 1.0f / Nn);
}

// Round 12
// 314.077 us; speedup vs baseline: 1.0520x; 1.0258x over previous
//
#include <hip/hip_runtime.h>
#include <hip/hip_bf16.h>
#include <math.h>

#define Nn 20000
#define Ee 320000
#define INF_ 256
#define Hh 4
#define Cc 64
#define HC 256
#define NEG_SLOPE 0.2f
#define NB 79           // ceil(Nn/256)

using frag16 = __attribute__((ext_vector_type(8))) short;   // 8 bf16 (4 VGPRs)
using f32x4  = __attribute__((ext_vector_type(4))) float;

// async global->LDS 16B per lane; LDS dest = wave-uniform base + lane*16
__device__ __forceinline__ void async16(const void* g, void* l) {
    __builtin_amdgcn_global_load_lds(
        (const __attribute__((address_space(1))) unsigned int*)g,
        (__attribute__((address_space(3))) unsigned int*)l,
        16, 0, 0);
}

// ---------------- CSR build (6 small dispatches; R8: coop grid.sync costs
// ~30us/barrier on 8 XCDs -- kernel boundaries are the cheap grid barrier) --

__global__ void init_deg(int* deg, int n) {
    int i = blockIdx.x * blockDim.x + threadIdx.x;
    if (i < n) deg[i] = 1;  // self-loop pre-counted
}

__global__ void hist_kernel(const int* __restrict__ dst, int ne, int* deg) {
    int e = blockIdx.x * blockDim.x + threadIdx.x;
    if (e < ne) atomicAdd(&deg[dst[e]], 1);
}

__global__ __launch_bounds__(256) void scan1(const int* __restrict__ deg,
                                             int* __restrict__ excl,
                                             int* __restrict__ bsum, int n) {
    int tid = threadIdx.x;
    int gid = blockIdx.x * 256 + tid;
    int lane = tid & 63;
    int v = (gid < n) ? deg[gid] : 0;
    int x = v;
    #pragma unroll
    for (int off = 1; off < 64; off <<= 1) {
        int y = __shfl_up(x, off, 64);
        if (lane >= off) x += y;
    }
    __shared__ int wsum[4];
    if (lane == 63) wsum[tid >> 6] = x;
    __syncthreads();
    int wadd = 0;
    for (int w = 0; w < (tid >> 6); ++w) wadd += wsum[w];
    int incl = x + wadd;
    if (gid < n) excl[gid] = incl - v;
    if (tid == 255) bsum[blockIdx.x] = incl;
}

__global__ void scan2(const int* __restrict__ bsum, int* __restrict__ boff, int nb) {
    int lane = threadIdx.x;
    int carry = 0;
    for (int base = 0; base < nb; base += 64) {
        int i = base + lane;
        int v = (i < nb) ? bsum[i] : 0;
        int x = v;
        #pragma unroll
        for (int off = 1; off < 64; off <<= 1) {
            int y = __shfl_up(x, off, 64);
            if (lane >= off) x += y;
        }
        if (i < nb) boff[i] = carry + x - v;
        carry += __shfl(x, 63, 64);
    }
    if (lane == 0) boff[nb] = carry;
}

__global__ void scan_add(int* __restrict__ row_start, int* __restrict__ cursor,
                         const int* __restrict__ boff, int n, int nb) {
    int gid = blockIdx.x * blockDim.x + threadIdx.x;
    if (gid < n) {
        int v = row_start[gid] + boff[gid >> 8];
        row_start[gid] = v;
        cursor[gid] = v;
    }
    if (gid == n) row_start[n] = boff[nb];
}

__global__ void scatter_kernel(const int* __restrict__ src, const int* __restrict__ dst,
                               int ne, int n, int* cursor, int* colx) {
    int e = blockIdx.x * blockDim.x + threadIdx.x;
    if (e < ne) {
        int d = dst[e];
        int pos = atomicAdd(&cursor[d], 1);
        colx[pos] = src[e];
    } else if (e < ne + n) {
        int node = e - ne;
        int pos = atomicAdd(&cursor[node], 1);
        colx[pos] = node;  // self-loop
    }
}

// ---------------- bf16 split-precision helpers ----------------

__device__ inline unsigned short bf16rn(float f) {
    unsigned u = __float_as_uint(f);
    unsigned r = (u + 0x7FFFu + ((u >> 16) & 1u)) >> 16;   // RTNE
    return (unsigned short)r;
}

__device__ inline void split1(float v, short& h, short& l) {
    unsigned short hh = bf16rn(v);
    float back = __uint_as_float(((unsigned)hh) << 16);
    unsigned short ll = bf16rn(v - back);
    h = (short)hh; l = (short)ll;
}

__device__ __forceinline__ float4 bf4_to_f4(ushort4 u) {
    return make_float4(__uint_as_float((unsigned)u.x << 16),
                       __uint_as_float((unsigned)u.y << 16),
                       __uint_as_float((unsigned)u.z << 16),
                       __uint_as_float((unsigned)u.w << 16));
}

// ---------------- fused prep: weight split (both layers) + x split ----------

__global__ __launch_bounds__(256) void prep_kernel(const float* __restrict__ x,
                                                   const float* __restrict__ Wl1,
                                                   const float* __restrict__ Wr1,
                                                   const float* __restrict__ Wl2,
                                                   const float* __restrict__ Wr2,
                                                   short* __restrict__ WhT1,
                                                   short* __restrict__ WlT1,
                                                   short* __restrict__ WhT2,
                                                   short* __restrict__ WlT2,
                                                   short* __restrict__ Ah,
                                                   short* __restrict__ Al,
                                                   float* __restrict__ g,
                                                   int* __restrict__ fcnt, int n4) {
    int b = blockIdx.x;
    if (b < 1024) {
        int n = b & 255;
        int k = threadIdx.x;
        if (b == 0) {
            g[k] = 0.f;                  // HC == 256 == blockDim
            if (k == 0) *fcnt = 0;
        }
        const float* W = (b < 256) ? Wl1 : (b < 512) ? Wr1 : (b < 768) ? Wl2 : Wr2;
        short* Wh = (b < 512) ? WhT1 : WhT2;
        short* Wl = (b < 512) ? WlT1 : WlT2;
        int col = b & 511;
        float v = W[k * 256 + n];
        short h, l;
        split1(v, h, l);
        Wh[col * 256 + k] = h;
        Wl[col * 256 + k] = l;
    } else {
        int i = (b - 1024) * 256 + threadIdx.x;
        if (i >= n4) return;
        float4 v = ((const float4*)x)[i];
        short4 h, l;
        split1(v.x, h.x, l.x);
        split1(v.y, h.y, l.y);
        split1(v.z, h.z, l.z);
        split1(v.w, h.w, l.w);
        ((short4*)Ah)[i] = h;
        ((short4*)Al)[i] = l;
    }
}

// ---------------- bf16x3 MFMA fused GEMM, 64x64 tiles, pipelined dbuf -------
// [XL | XR] = A @ [Wl | Wr],  C = Ah*Wh + Al*Wh + Ah*Wl (bf16x3 split).
// 64x64 tile -> ~2504 live blocks, 32 KB LDS dbuf -> 5 blocks/CU.
// XCD-aware flat-grid swizzle: row-blocks == XCD (id%8), col fastest.
// Single barrier/chunk: sync -> stage c+1 (other buf) -> compute c.
// XOR k-slot swizzle on fetch & read sides -> ds_read_b128 2-way only.
// Wave w stages tile w (A_h/A_l/B_h/B_l) and computes n-strip w.

#define BK 32

__global__ __launch_bounds__(256) void mfma_gemm(const short* __restrict__ Ah,
                                                 const short* __restrict__ Al,
                                                 const short* __restrict__ WhT,
                                                 const short* __restrict__ WlT,
                                                 unsigned short* __restrict__ XLh,
                                                 float* __restrict__ XR) {
    __shared__ short S[2][4][64 * BK];        // [buf][tile: Ah,Al,Bh,Bl]
    int tid = threadIdx.x;
    int wave = tid >> 6, lane = tid & 63;
    int quad = lane >> 4, lc = lane & 15;

    int flat = blockIdx.x;                    // 0..2559 (320 row-blocks x 8)
    int xcd = flat & 7;
    int slot = flat >> 3;                     // 0..319
    int rb = xcd + 8 * (slot >> 3);           // row-block; ==xcd (mod 8)
    int bxc = slot & 7;                       // col-group (64 concat cols)
    int bm = rb * 64;
    if (bm >= Nn) return;                     // padding blocks (rb >= 313)
    int cbase = (bxc * 64) & 255;

    // staging: wave stages its tile with 4 async16 calls; call i covers rows
    // i*16 + (lane>>2), 16B k-slot (lane&3) XOR-swizzled.
    int srow = lane >> 2;
    int swz = ((lane >> 2) ^ (lane >> 4)) & 3;
    int koff = ((lane & 3) ^ swz) * 8;
    const short* mat = (wave == 0) ? Ah : (wave == 1) ? Al
                     : (wave == 2) ? WhT : WlT;
    int grow_base = (wave < 2) ? bm : bxc * 64;
    const short* gp[4];
    #pragma unroll
    for (int i = 0; i < 4; ++i) {
        int grow = grow_base + i * 16 + srow;
        if (wave < 2 && grow >= Nn) grow = Nn - 1;   // clamp (rows independent)
        gp[i] = mat + (size_t)grow * HC + koff;
    }

    auto stage = [&](int c, int d) {
        int k0 = c * BK;
        #pragma unroll
        for (int i = 0; i < 4; ++i)
            async16(gp[i] + k0, &S[d][wave][i * 512]);
    };

    // read-side swizzle: frag (row, kb=quad) lives at slot quad ^ rs(lc)
    int rs = (lc ^ (lc >> 2)) & 3;
    int akb = (quad ^ rs) * 8;

    f32x4 acc[4] = {};
    stage(0, 0);
    for (int c = 0; c < 8; ++c) {
        __syncthreads();                 // chunk c staged; prev compute done
        if (c < 7) stage(c + 1, (c + 1) & 1);
        int d = c & 1;
        frag16 bh = *(const frag16*)&S[d][2][(wave * 16 + lc) * BK + akb];
        frag16 bl = *(const frag16*)&S[d][3][(wave * 16 + lc) * BK + akb];
        #pragma unroll
        for (int mt = 0; mt < 4; ++mt) {
            frag16 amh = *(const frag16*)&S[d][0][(mt * 16 + lc) * BK + akb];
            frag16 aml = *(const frag16*)&S[d][1][(mt * 16 + lc) * BK + akb];
            acc[mt] = __builtin_amdgcn_mfma_f32_16x16x32_bf16(amh, bh, acc[mt], 0, 0, 0);
            acc[mt] = __builtin_amdgcn_mfma_f32_16x16x32_bf16(aml, bh, acc[mt], 0, 0, 0);
            acc[mt] = __builtin_amdgcn_mfma_f32_16x16x32_bf16(amh, bl, acc[mt], 0, 0, 0);
        }
    }
    // epilogue: wave's cols = cbase + wave*16 + lc; rows = bm + mt*16 + quad*4 + r
    int col = cbase + wave * 16 + lc;
    #pragma unroll
    for (int mt = 0; mt < 4; ++mt) {
        int rbase = bm + mt * 16 + quad * 4;
        #pragma unroll
        for (int r = 0; r < 4; ++r) {
            int rw = rbase + r;
            if (rw >= Nn) continue;
            if (bxc < 4) XLh[(size_t)rw * HC + col] = bf16rn(acc[mt][r]);
            else         XR [(size_t)rw * HC + col] = acc[mt][r];
        }
    }
}

// ---------------- GATv2 edge phase (R10 4-way version -- measured optimum;
// R11's 8-way regressed: VGPR 36->44, occupancy 48->36%, dur 49.7->55.9) ----
// One wave per node (4 nodes/block). Lane holds 4 channels; head h = lanes
// 16h..16h+15. XL gathered bf16 (8 B/lane); XR/bias fp32.
// No-max softmax (scores bounded << 88); leaky(t)=0.6t+0.4|t|.

__device__ __forceinline__ float edge_score(const float4 v, const float4 xr,
                                            const float4 a06, const float4 a04) {
    float tx = v.x + xr.x, ty = v.y + xr.y, tz = v.z + xr.z, tw = v.w + xr.w;
    float p = a06.x * tx + a04.x * fabsf(tx);
    p += a06.y * ty + a04.y * fabsf(ty);
    p += a06.z * tz + a04.z * fabsf(tz);
    p += a06.w * tw + a04.w * fabsf(tw);
    p += __shfl_xor(p, 1, 64);
    p += __shfl_xor(p, 2, 64);
    p += __shfl_xor(p, 4, 64);
    p += __shfl_xor(p, 8, 64);             // per-head score in its 16 lanes
    return p;
}

__global__ __launch_bounds__(256) void gat_kernel(const ushort4* __restrict__ XL4,
                                                  const float4* __restrict__ XR4,
                                                  const int* __restrict__ row_start,
                                                  const int* __restrict__ colx,
                                                  const float4* __restrict__ att4,
                                                  const float4* __restrict__ bias4,
                                                  float4* __restrict__ Hout,
                                                  short4* __restrict__ Ahi,
                                                  short4* __restrict__ Alo,
                                                  int mode) {
    int wave = threadIdx.x >> 6, lane = threadIdx.x & 63;
    int node = blockIdx.x * 4 + wave;          // grid = Nn/4 exactly
    float4 xr = XR4[(size_t)node * 64 + lane];
    float4 a  = att4[lane];
    float4 a06 = make_float4(a.x * 0.6f, a.y * 0.6f, a.z * 0.6f, a.w * 0.6f);
    float4 a04 = make_float4(a.x * 0.4f, a.y * 0.4f, a.z * 0.4f, a.w * 0.4f);
    int e0 = row_start[node], e1 = row_start[node + 1];
    float l0 = 0.f, l1 = 0.f, l2 = 0.f, l3 = 0.f;
    float4 acc0 = make_float4(0.f, 0.f, 0.f, 0.f);
    float4 acc1 = make_float4(0.f, 0.f, 0.f, 0.f);
    float4 acc2 = make_float4(0.f, 0.f, 0.f, 0.f);
    float4 acc3 = make_float4(0.f, 0.f, 0.f, 0.f);
    int e = e0;
    for (; e + 3 < e1; e += 4) {
        int s0 = __builtin_amdgcn_readfirstlane(colx[e]);
        int s1 = __builtin_amdgcn_readfirstlane(colx[e + 1]);
        int s2 = __builtin_amdgcn_readfirstlane(colx[e + 2]);
        int s3 = __builtin_amdgcn_readfirstlane(colx[e + 3]);
        float4 v0 = bf4_to_f4(XL4[(size_t)s0 * 64 + lane]);
        float4 v1 = bf4_to_f4(XL4[(size_t)s1 * 64 + lane]);
        float4 v2 = bf4_to_f4(XL4[(size_t)s2 * 64 + lane]);
        float4 v3 = bf4_to_f4(XL4[(size_t)s3 * 64 + lane]);
        float pe0 = __expf(edge_score(v0, xr, a06, a04));
        float pe1 = __expf(edge_score(v1, xr, a06, a04));
        float pe2 = __expf(edge_score(v2, xr, a06, a04));
        float pe3 = __expf(edge_score(v3, xr, a06, a04));
        l0 += pe0; l1 += pe1; l2 += pe2; l3 += pe3;
        acc0.x += pe0 * v0.x; acc0.y += pe0 * v0.y; acc0.z += pe0 * v0.z; acc0.w += pe0 * v0.w;
        acc1.x += pe1 * v1.x; acc1.y += pe1 * v1.y; acc1.z += pe1 * v1.z; acc1.w += pe1 * v1.w;
        acc2.x += pe2 * v2.x; acc2.y += pe2 * v2.y; acc2.z += pe2 * v2.z; acc2.w += pe2 * v2.w;
        acc3.x += pe3 * v3.x; acc3.y += pe3 * v3.y; acc3.z += pe3 * v3.z; acc3.w += pe3 * v3.w;
    }
    for (; e < e1; ++e) {
        int s0 = __builtin_amdgcn_readfirstlane(colx[e]);
        float4 v0 = bf4_to_f4(XL4[(size_t)s0 * 64 + lane]);
        float pe0 = __expf(edge_score(v0, xr, a06, a04));
        l0 += pe0;
        acc0.x += pe0 * v0.x; acc0.y += pe0 * v0.y;
        acc0.z += pe0 * v0.z; acc0.w += pe0 * v0.w;
    }
    float rl = 1.f / (l0 + l1 + l2 + l3);
    float4 b = bias4[lane];
    float4 o = make_float4(fmaxf((acc0.x + acc1.x + acc2.x + acc3.x) * rl + b.x, 0.f),
                           fmaxf((acc0.y + acc1.y + acc2.y + acc3.y) * rl + b.y, 0.f),
                           fmaxf((acc0.z + acc1.z + acc2.z + acc3.z) * rl + b.z, 0.f),
                           fmaxf((acc0.w + acc1.w + acc2.w + acc3.w) * rl + b.w, 0.f));
    size_t oidx = (size_t)node * 64 + lane;
    if (mode) {
        short4 h4, l4;
        split1(o.x, h4.x, l4.x);
        split1(o.y, h4.y, l4.y);
        split1(o.z, h4.z, l4.z);
        split1(o.w, h4.w, l4.w);
        Ahi[oidx] = h4;
        Alo[oidx] = l4;
    } else {
        Hout[oidx] = o;
    }
}

// ---------------- fused pooling + FC (last-block pattern) ----------------
// g and fcnt are zero-inited by prep_kernel at the start of the launch.

__global__ __launch_bounds__(256) void colsum_fc(const float* __restrict__ Hmat,
                                                 float* __restrict__ g,
                                                 int* __restrict__ fcnt,
                                                 const float* __restrict__ Wfc,
                                                 const float* __restrict__ bfc,
                                                 float* __restrict__ out, float invN) {
    int ch = threadIdx.x;
    float s = 0.f;
    for (int r = blockIdx.x; r < Nn; r += gridDim.x)
        s += Hmat[(size_t)r * HC + ch];
    atomicAdd(&g[ch], s);
    __threadfence();
    __shared__ int last;
    if (ch == 0) last = (atomicAdd(fcnt, 1) == (int)gridDim.x - 1);
    __syncthreads();
    if (!last) return;
    // last block: all partial sums visible; read via atomic (L1-bypass)
    float gv = atomicAdd(&g[ch], 0.f) * invN;
    float p0 = gv * Wfc[2 * ch];
    float p1 = gv * Wfc[2 * ch + 1];
    #pragma unroll
    for (int off = 32; off > 0; off >>= 1) {
        p0 += __shfl_xor(p0, off, 64);
        p1 += __shfl_xor(p1, off, 64);
    }
    __shared__ float s0[4], s1[4];
    if ((ch & 63) == 0) { s0[ch >> 6] = p0; s1[ch >> 6] = p1; }
    __syncthreads();
    if (ch == 0) {
        out[0] = s0[0] + s0[1] + s0[2] + s0[3] + bfc[0];
        out[1] = s1[0] + s1[1] + s1[2] + s1[3] + bfc[1];
    }
}

// ---------------- launch ----------------

extern "C" void kernel_launch(void* const* d_in, const int* in_sizes, int n_in,
                              void* d_out, int out_size, void* d_ws, size_t ws_size,
                              hipStream_t stream) {
    const float* x    = (const float*)d_in[0];
    const int*   eidx = (const int*)d_in[1];   // (2,E) row-major: [src | dst]
    const float* Wl1  = (const float*)d_in[2];
    const float* Wr1  = (const float*)d_in[3];
    const float* att1 = (const float*)d_in[4];
    const float* b1   = (const float*)d_in[5];
    const float* Wl2  = (const float*)d_in[6];
    const float* Wr2  = (const float*)d_in[7];
    const float* att2 = (const float*)d_in[8];
    const float* b2   = (const float*)d_in[9];
    const float* Wfc  = (const float*)d_in[10];
    const float* bfc  = (const float*)d_in[11];
    float* out = (float*)d_out;

    const int* srcv = eidx;
    const int* dstv = eidx + Ee;

    // workspace layout (~75 MB)
    size_t NHC = (size_t)Nn * HC;
    float* XR = (float*)d_ws;
    float* Hb = XR + NHC;
    float* g  = Hb + NHC;
    unsigned short* XLh = (unsigned short*)(g + HC);
    short* Ah   = (short*)(XLh + NHC);
    short* Al   = Ah + NHC;
    short* WhT1 = Al + NHC;                    // 512*256 concat [Wl|Wr]^T per layer
    short* WlT1 = WhT1 + 512 * 256;
    short* WhT2 = WlT1 + 512 * 256;
    short* WlT2 = WhT2 + 512 * 256;
    int* deg       = (int*)(WlT2 + 512 * 256);
    int* row_start = deg + Nn;
    int* cursor    = row_start + (Nn + 1);
    int* colx      = cursor + Nn;              // Ee + Nn entries
    int* bsum      = colx + (Ee + Nn);
    int* boff      = bsum + 128;               // NB+1 entries
    int* fcnt      = boff + 128;

    const int N4 = (int)(NHC / 4);             // 1,280,000 (5000 x-split blocks)

    // CSR build (6 small dispatches)
    init_deg<<<(Nn + 255) / 256, 256, 0, stream>>>(deg, Nn);
    hist_kernel<<<(Ee + 255) / 256, 256, 0, stream>>>(dstv, Ee, deg);
    scan1<<<NB, 256, 0, stream>>>(deg, row_start, bsum, Nn);
    scan2<<<1, 64, 0, stream>>>(bsum, boff, NB);
    scan_add<<<(Nn + 256) / 256, 256, 0, stream>>>(row_start, cursor, boff, Nn, NB);
    scatter_kernel<<<(Ee + Nn + 255) / 256, 256, 0, stream>>>(srcv, dstv, Ee, Nn, cursor, colx);

    // weight split (both layers) + layer-1 input split + g/fcnt zero: 1 dispatch
    prep_kernel<<<1024 + N4 / 256, 256, 0, stream>>>(x, Wl1, Wr1, Wl2, Wr2,
                                                     WhT1, WlT1, WhT2, WlT2,
                                                     Ah, Al, g, fcnt, N4);

    // 64x64 tiles, XCD-swizzled flat grid: 320 row-blocks x 8 col-groups
    const int GEMM_BLOCKS = 320 * 8;

    // layer 1 (gat writes bf16 split directly -> layer-2 GEMM input)
    mfma_gemm<<<GEMM_BLOCKS, 256, 0, stream>>>(Ah, Al, WhT1, WlT1, XLh, XR);
    gat_kernel<<<Nn / 4, 256, 0, stream>>>((const ushort4*)XLh, (const float4*)XR,
                                           row_start, colx, (const float4*)att1,
                                           (const float4*)b1, (float4*)Hb,
                                           (short4*)Ah, (short4*)Al, 1);

    // layer 2
    mfma_gemm<<<GEMM_BLOCKS, 256, 0, stream>>>(Ah, Al, WhT2, WlT2, XLh, XR);
    gat_kernel<<<Nn / 4, 256, 0, stream>>>((const ushort4*)XLh, (const float4*)XR,
                                           row_start, colx, (const float4*)att2,
                                           (const float4*)b2, (float4*)Hb,
                                           (short4*)Ah, (short4*)Al, 0);

    // pool + fc (fused, last-block pattern)
    colsum_fc<<<256, 256, 0, stream>>>(Hb, g, fcnt, Wfc, bfc, out, 1.0f / Nn);
}